// Round 1
// baseline (2730.515 us; speedup 1.0000x reference)
//
#include <hip/hip_runtime.h>
#include <math.h>

constexpr int NN = 4096, DD = 64, TT = 60, HH = 128, GG = 512, KK = 192;

// ws layout (float offsets)
constexpr size_t XNT = 0;                                 // [T][N][D]
constexpr size_t WTO = XNT + (size_t)TT * NN * DD;        // [192][512] transposed combined weights
constexpr size_t BSUM = WTO + (size_t)KK * GG;            // [512]
constexpr size_t SC1 = BSUM + GG;                         // [64]
constexpr size_t SH1 = SC1 + DD;                          // [64]
constexpr size_t HID = SH1 + DD;                          // [N][H]
constexpr size_t HBN = HID + (size_t)NN * HH;             // [N][H]
constexpr size_t SC2 = HBN + (size_t)NN * HH;             // [128]
constexpr size_t SH2 = SC2 + HH;
constexpr size_t U1O = SH2 + HH;
constexpr size_t U2O = U1O + HH;
constexpr size_t CCO = U2O + HH;                          // [4]
constexpr size_t S1O = CCO + 4;                           // [N]
constexpr size_t S2O = S1O + NN;
constexpr size_t MRO = S2O + NN;
constexpr size_t SRO = MRO + NN;
constexpr size_t H2O = SRO + NN;                          // [N][H]

__device__ __forceinline__ float sigmoidf_(float x) { return 1.f / (1.f + __expf(-x)); }
__device__ __forceinline__ float tanhfast_(float x) { return 1.f - 2.f / (__expf(2.f * x) + 1.f); }
__device__ __forceinline__ float leakyf_(float z) { return z >= 0.f ? z : 0.01f * z; }

// ---- prep: transposed combined weights WT[d][j], bsum ----
__global__ void k_prep_w(const float* __restrict__ Wih, const float* __restrict__ Whh,
                         const float* __restrict__ bih, const float* __restrict__ bhh,
                         float* __restrict__ ws) {
    int o = blockIdx.x * 256 + threadIdx.x;
    if (o < KK * GG) {
        int d = o >> 9, j = o & 511;
        ws[WTO + o] = (d < DD) ? Wih[j * DD + d] : Whh[j * HH + (d - DD)];
    }
    if (o < GG) ws[BSUM + o] = bih[o] + bhh[o];
}

// ---- prep: u1 = W_t^T a1, u2 = W_t^T a2, c1 = b_t.a1, c2 = b_t.a2 ----
__global__ void k_prep_uv(const float* __restrict__ Wt, const float* __restrict__ bt,
                          const float* __restrict__ a, float* __restrict__ ws) {
    int k = threadIdx.x;  // 0..127
    float u1 = 0.f, u2 = 0.f;
    for (int j = 0; j < HH; j++) {
        float w = Wt[j * HH + k];
        u1 = fmaf(w, a[j], u1);
        u2 = fmaf(w, a[HH + j], u2);
    }
    ws[U1O + k] = u1;
    ws[U2O + k] = u2;
    if (k == 0) {
        float c1 = 0.f, c2 = 0.f;
        for (int j = 0; j < HH; j++) {
            c1 = fmaf(bt[j], a[j], c1);
            c2 = fmaf(bt[j], a[HH + j], c2);
        }
        ws[CCO] = c1;
        ws[CCO + 1] = c2;
    }
}

// ---- BN1 stats per channel d ----
__global__ void k_bn1_stats(const float* __restrict__ x, const float* __restrict__ g1,
                            const float* __restrict__ b1, float* __restrict__ ws) {
    int d = blockIdx.x, tid = threadIdx.x;
    float s = 0.f, ss = 0.f;
    for (int i = tid; i < NN * TT; i += 256) {
        int n = i / TT, t = i - n * TT;
        float v = x[((size_t)n * DD + d) * TT + t];
        s += v;
        ss = fmaf(v, v, ss);
    }
    __shared__ float rs[256], rss[256];
    rs[tid] = s; rss[tid] = ss;
    __syncthreads();
    for (int st = 128; st > 0; st >>= 1) {
        if (tid < st) { rs[tid] += rs[tid + st]; rss[tid] += rss[tid + st]; }
        __syncthreads();
    }
    if (tid == 0) {
        float m = rs[0] / (float)(NN * TT);
        float var = rss[0] / (float)(NN * TT) - m * m;
        float sc = g1[d] * rsqrtf(var + 1e-5f);
        ws[SC1 + d] = sc;
        ws[SH1 + d] = b1[d] - m * sc;
    }
}

// ---- BN1 apply + transpose to xnT[t][n][d] ----
__global__ void k_bn1_apply(const float* __restrict__ x, float* __restrict__ ws) {
    int n = blockIdx.x, tid = threadIdx.x;
    __shared__ float lx[DD * 61];
    __shared__ float sc[DD], sh[DD];
    if (tid < DD) { sc[tid] = ws[SC1 + tid]; sh[tid] = ws[SH1 + tid]; }
    const float* xr = x + (size_t)n * DD * TT;
    for (int i = tid; i < DD * TT; i += 256) {
        int d = i / TT, t = i - d * TT;
        lx[d * 61 + t] = xr[i];
    }
    __syncthreads();
    float* out = ws + XNT;
    for (int i = tid; i < TT * DD; i += 256) {
        int t = i >> 6, d = i & 63;
        out[((size_t)t * NN + n) * DD + d] = fmaf(lx[d * 61 + t], sc[d], sh[d]);
    }
}

// ---- LSTM persistent kernel: 256 blocks x 16 rows ----
__global__ __launch_bounds__(256) void k_lstm(float* __restrict__ ws) {
    int tid = threadIdx.x;
    int r0 = blockIdx.x * 16;
    __shared__ float intile[16][KK];  // [x(64) | h(128)] per row
    __shared__ float gbuf[16][GG];
    __shared__ float cst[16][HH];
    const float* __restrict__ WTb = ws + WTO;
    float bs0 = ws[BSUM + tid], bs1 = ws[BSUM + 256 + tid];
    for (int p = tid; p < 16 * HH; p += 256) {
        int r = p >> 7, k = p & 127;
        cst[r][k] = 0.f;
        intile[r][DD + k] = 0.f;
    }
    __syncthreads();
    for (int t = 0; t < TT; t++) {
        const float* xt = ws + XNT + ((size_t)t * NN + r0) * DD;
        for (int p = tid; p < 16 * DD; p += 256) intile[p >> 6][p & 63] = xt[p];
        __syncthreads();
        float acc0[16], acc1[16];
#pragma unroll
        for (int r = 0; r < 16; r++) { acc0[r] = 0.f; acc1[r] = 0.f; }
#pragma unroll 2
        for (int d0 = 0; d0 < KK; d0 += 4) {
            const float* wp = WTb + (size_t)d0 * GG + tid;
            float w00 = wp[0], w01 = wp[GG], w02 = wp[2 * GG], w03 = wp[3 * GG];
            float w10 = wp[256], w11 = wp[GG + 256], w12 = wp[2 * GG + 256], w13 = wp[3 * GG + 256];
#pragma unroll
            for (int r = 0; r < 16; r++) {
                float4 v = *(const float4*)&intile[r][d0];
                acc0[r] = fmaf(v.x, w00, fmaf(v.y, w01, fmaf(v.z, w02, fmaf(v.w, w03, acc0[r]))));
                acc1[r] = fmaf(v.x, w10, fmaf(v.y, w11, fmaf(v.z, w12, fmaf(v.w, w13, acc1[r]))));
            }
        }
#pragma unroll
        for (int r = 0; r < 16; r++) {
            gbuf[r][tid] = acc0[r] + bs0;
            gbuf[r][256 + tid] = acc1[r] + bs1;
        }
        __syncthreads();
        for (int p = tid; p < 16 * HH; p += 256) {
            int r = p >> 7, k = p & 127;
            float ig = sigmoidf_(gbuf[r][k]);
            float fg = sigmoidf_(gbuf[r][HH + k]);
            float gg = tanhfast_(gbuf[r][2 * HH + k]);
            float og = sigmoidf_(gbuf[r][3 * HH + k]);
            float c = fmaf(fg, cst[r][k], ig * gg);
            cst[r][k] = c;
            intile[r][DD + k] = og * tanhfast_(c);
        }
        __syncthreads();
    }
    for (int p = tid; p < 16 * HH; p += 256) {
        int r = p >> 7, k = p & 127;
        ws[HID + (size_t)(r0 + r) * HH + k] = intile[r][DD + k];
    }
}

// ---- BN2 stats per column k ----
__global__ void k_bn2_stats(const float* __restrict__ g2, const float* __restrict__ b2,
                            float* __restrict__ ws) {
    int k = blockIdx.x, tid = threadIdx.x;
    float s = 0.f, ss = 0.f;
    for (int n = tid; n < NN; n += 256) {
        float v = ws[HID + (size_t)n * HH + k];
        s += v;
        ss = fmaf(v, v, ss);
    }
    __shared__ float rs[256], rss[256];
    rs[tid] = s; rss[tid] = ss;
    __syncthreads();
    for (int st = 128; st > 0; st >>= 1) {
        if (tid < st) { rs[tid] += rs[tid + st]; rss[tid] += rss[tid + st]; }
        __syncthreads();
    }
    if (tid == 0) {
        float m = rs[0] / (float)NN;
        float var = rss[0] / (float)NN - m * m;
        float sc = g2[k] * rsqrtf(var + 1e-5f);
        ws[SC2 + k] = sc;
        ws[SH2 + k] = b2[k] - m * sc;
    }
}

// ---- apply BN2, compute s1, s2 ----
__global__ void k_hbn(float* __restrict__ ws) {
    __shared__ float sc[HH], sh[HH], u1s[HH], u2s[HH];
    int tid = threadIdx.x;
    if (tid < HH) {
        sc[tid] = ws[SC2 + tid]; sh[tid] = ws[SH2 + tid];
        u1s[tid] = ws[U1O + tid]; u2s[tid] = ws[U2O + tid];
    }
    __syncthreads();
    int r = tid >> 3, l = tid & 7;
    int n = blockIdx.x * 32 + r;
    const float* hr = ws + HID + (size_t)n * HH;
    float* hb = ws + HBN + (size_t)n * HH;
    float d1 = 0.f, d2 = 0.f;
    int k0 = l * 16;
#pragma unroll
    for (int q = 0; q < 16; q++) {
        int kk = k0 + q;
        float v = fmaf(hr[kk], sc[kk], sh[kk]);
        hb[kk] = v;
        d1 = fmaf(v, u1s[kk], d1);
        d2 = fmaf(v, u2s[kk], d2);
    }
#pragma unroll
    for (int o = 1; o < 8; o <<= 1) { d1 += __shfl_xor(d1, o, 64); d2 += __shfl_xor(d2, o, 64); }
    if (l == 0) {
        ws[S1O + n] = d1 + ws[CCO];
        ws[S2O + n] = d2 + ws[CCO + 1];
    }
}

// ---- softmax stats per row: max and sum of exp ----
__global__ void k_msum(float* __restrict__ ws) {
    __shared__ float ls1[NN];
    int tid = threadIdx.x;
    for (int i = tid; i < NN; i += 256) ls1[i] = ws[S1O + i];
    __syncthreads();
    int r = tid >> 3, l = tid & 7;
    int n = blockIdx.x * 32 + r;
    float s2i = ws[S2O + n];
    float m = -1e30f;
    for (int j = l; j < NN; j += 8) m = fmaxf(m, leakyf_(s2i + ls1[j]));
#pragma unroll
    for (int o = 1; o < 8; o <<= 1) m = fmaxf(m, __shfl_xor(m, o, 64));
    float se = 0.f;
    for (int j = l; j < NN; j += 8) se += __expf(leakyf_(s2i + ls1[j]) - m);
#pragma unroll
    for (int o = 1; o < 8; o <<= 1) se += __shfl_xor(se, o, 64);
    if (l == 0) { ws[MRO + n] = m; ws[SRO + n] = se; }
}

// ---- attention: h2 = softmax(scores) @ hbn + hbn ----
__global__ __launch_bounds__(256) void k_att(float* __restrict__ ws) {
    __shared__ float ls1[NN];
    int tid = threadIdx.x;
    for (int i = tid; i < NN; i += 256) ls1[i] = ws[S1O + i];
    __syncthreads();
    int rt = blockIdx.x & 15, hs = blockIdx.x >> 4;
    int n = rt * 256 + tid;
    int h0 = hs * 8;
    float s2i = ws[S2O + n];
    float mi = ws[MRO + n];
    float inv = 1.f / ws[SRO + n];
    float acc[8];
#pragma unroll
    for (int q = 0; q < 8; q++) acc[q] = 0.f;
    const float4* hb4 = (const float4*)(ws + HBN);
    int hq = h0 >> 2;
#pragma unroll 4
    for (int j = 0; j < NN; j++) {
        float w = __expf(leakyf_(s2i + ls1[j]) - mi);
        float4 a0 = hb4[(size_t)j * 32 + hq];
        float4 a1 = hb4[(size_t)j * 32 + hq + 1];
        acc[0] = fmaf(w, a0.x, acc[0]); acc[1] = fmaf(w, a0.y, acc[1]);
        acc[2] = fmaf(w, a0.z, acc[2]); acc[3] = fmaf(w, a0.w, acc[3]);
        acc[4] = fmaf(w, a1.x, acc[4]); acc[5] = fmaf(w, a1.y, acc[5]);
        acc[6] = fmaf(w, a1.z, acc[6]); acc[7] = fmaf(w, a1.w, acc[7]);
    }
    float* h2 = ws + H2O + (size_t)n * HH + h0;
    const float* hbs = ws + HBN + (size_t)n * HH + h0;
#pragma unroll
    for (int q = 0; q < 8; q++) h2[q] = fmaf(acc[q], inv, hbs[q]);
}

// ---- final fc + leaky + out projection + sigmoid ----
__global__ __launch_bounds__(256) void k_fc(const float* __restrict__ Wfc, const float* __restrict__ bfc,
                                            const float* __restrict__ Wout, const float* __restrict__ bout,
                                            float* __restrict__ ws, float* __restrict__ out) {
    __shared__ float h2r[32][HH + 4];
    int tid = threadIdx.x;
    int n0 = blockIdx.x * 32;
    for (int p = tid; p < 32 * HH; p += 256) h2r[p >> 7][p & 127] = ws[H2O + (size_t)n0 * HH + p];
    __syncthreads();
    int r = tid >> 3, l = tid & 7;
    int n = n0 + r;
    float po = 0.f;
    for (int jj = 0; jj < 16; jj++) {
        int j = l * 16 + jj;
        const float4* wrow = (const float4*)(Wfc + (size_t)j * HH);
        float acc = 0.f;
#pragma unroll 8
        for (int q = 0; q < 32; q++) {
            float4 wv = wrow[q];
            float4 hv = *(const float4*)&h2r[r][q * 4];
            acc = fmaf(wv.x, hv.x, fmaf(wv.y, hv.y, fmaf(wv.z, hv.z, fmaf(wv.w, hv.w, acc))));
        }
        float h3 = leakyf_(acc + bfc[j]);
        po = fmaf(h3, Wout[j], po);
    }
#pragma unroll
    for (int o = 1; o < 8; o <<= 1) po += __shfl_xor(po, o, 64);
    if (l == 0) out[n] = 1.f / (1.f + __expf(-(po + bout[0])));
}

extern "C" void kernel_launch(void* const* d_in, const int* in_sizes, int n_in,
                              void* d_out, int out_size, void* d_ws, size_t ws_size,
                              hipStream_t stream) {
    const float* x = (const float*)d_in[0];
    const float* bn1_g = (const float*)d_in[1];
    const float* bn1_b = (const float*)d_in[2];
    const float* W_ih = (const float*)d_in[3];
    const float* W_hh = (const float*)d_in[4];
    const float* b_ih = (const float*)d_in[5];
    const float* b_hh = (const float*)d_in[6];
    const float* bn2_g = (const float*)d_in[7];
    const float* bn2_b = (const float*)d_in[8];
    const float* W_t = (const float*)d_in[9];
    const float* b_t = (const float*)d_in[10];
    const float* a = (const float*)d_in[11];
    const float* W_fc = (const float*)d_in[12];
    const float* b_fc = (const float*)d_in[13];
    const float* W_out = (const float*)d_in[14];
    const float* b_out = (const float*)d_in[15];
    float* ws = (float*)d_ws;
    float* out = (float*)d_out;

    k_prep_w<<<(KK * GG + 255) / 256, 256, 0, stream>>>(W_ih, W_hh, b_ih, b_hh, ws);
    k_prep_uv<<<1, 128, 0, stream>>>(W_t, b_t, a, ws);
    k_bn1_stats<<<DD, 256, 0, stream>>>(x, bn1_g, bn1_b, ws);
    k_bn1_apply<<<NN, 256, 0, stream>>>(x, ws);
    k_lstm<<<NN / 16, 256, 0, stream>>>(ws);
    k_bn2_stats<<<HH, 256, 0, stream>>>(bn2_g, bn2_b, ws);
    k_hbn<<<NN / 32, 256, 0, stream>>>(ws);
    k_msum<<<NN / 32, 256, 0, stream>>>(ws);
    k_att<<<256, 256, 0, stream>>>(ws);
    k_fc<<<NN / 32, 256, 0, stream>>>(W_fc, b_fc, W_out, b_out, ws, out);
}

// Round 2
// 1110.541 us; speedup vs baseline: 2.4587x; 2.4587x over previous
//
#include <hip/hip_runtime.h>
#include <math.h>

constexpr int NN = 4096, DD = 64, TT = 60, HH = 128, GG = 512, KK = 192;

typedef _Float16 h8 __attribute__((ext_vector_type(8)));
typedef float f4 __attribute__((ext_vector_type(4)));

// ws layout (float offsets)
constexpr size_t XNT = 0;                                  // half [T][N][D] = 15728640 halves
constexpr size_t WFRG = (size_t)TT * NN * DD / 2;          // half [w][tg][ks][lane][8] = 98304 halves
constexpr size_t BSUM = WFRG + 98304 / 2;                  // [512] f32
constexpr size_t SC1 = BSUM + GG;                          // [64]
constexpr size_t SH1 = SC1 + DD;                           // [64]
constexpr size_t HID = SH1 + DD;                           // [N][H] f32
constexpr size_t HBN = HID + (size_t)NN * HH;              // [N][H]
constexpr size_t SC2 = HBN + (size_t)NN * HH;              // [128]
constexpr size_t SH2 = SC2 + HH;
constexpr size_t U1O = SH2 + HH;
constexpr size_t U2O = U1O + HH;
constexpr size_t CCO = U2O + HH;                           // [4]
constexpr size_t S1O = CCO + 4;                            // [N]
constexpr size_t S2O = S1O + NN;
constexpr size_t MRO = S2O + NN;
constexpr size_t SRO = MRO + NN;
constexpr size_t H2O = SRO + NN;                           // [N][H]

__device__ __forceinline__ float sigmoidf_(float x) { return 1.f / (1.f + __expf(-x)); }
__device__ __forceinline__ float tanhfast_(float x) { return 1.f - 2.f / (__expf(2.f * x) + 1.f); }
__device__ __forceinline__ float leakyf_(float z) { return z >= 0.f ? z : 0.01f * z; }

// ---- prep: per-wave-fragment swizzled fp16 weights + bias sum ----
// frag value: B[k][col], col = g*128 + w*32 + s*16 + (lane&15), k = ks*32 + (lane>>4)*8 + j
__global__ void k_prep_w(const float* __restrict__ Wih, const float* __restrict__ Whh,
                         const float* __restrict__ bih, const float* __restrict__ bhh,
                         float* __restrict__ ws) {
    int o = blockIdx.x * 256 + threadIdx.x;  // 0 .. 98304
    _Float16* wf = (_Float16*)(ws + WFRG);
    if (o < 98304) {
        int j = o & 7;
        int lane = (o >> 3) & 63;
        int rest = o >> 9;
        int ks = rest % 6;
        int tgw = rest / 6;          // w*8 + tg
        int tg = tgw & 7, w = tgw >> 3;
        int g = tg >> 1, s = tg & 1;
        int col = g * 128 + w * 32 + s * 16 + (lane & 15);
        int k = ks * 32 + (lane >> 4) * 8 + j;
        float v = (k < DD) ? Wih[col * DD + k] : Whh[col * HH + (k - DD)];
        wf[o] = (_Float16)v;
    }
    if (o < GG) ws[BSUM + o] = bih[o] + bhh[o];
}

// ---- prep: u1 = W_t^T a1, u2 = W_t^T a2, c1 = b_t.a1, c2 = b_t.a2 ----
__global__ void k_prep_uv(const float* __restrict__ Wt, const float* __restrict__ bt,
                          const float* __restrict__ a, float* __restrict__ ws) {
    int k = threadIdx.x;  // 0..127
    float u1 = 0.f, u2 = 0.f;
    for (int j = 0; j < HH; j++) {
        float w = Wt[j * HH + k];
        u1 = fmaf(w, a[j], u1);
        u2 = fmaf(w, a[HH + j], u2);
    }
    ws[U1O + k] = u1;
    ws[U2O + k] = u2;
    if (k == 0) {
        float c1 = 0.f, c2 = 0.f;
        for (int j = 0; j < HH; j++) {
            c1 = fmaf(bt[j], a[j], c1);
            c2 = fmaf(bt[j], a[HH + j], c2);
        }
        ws[CCO] = c1;
        ws[CCO + 1] = c2;
    }
}

// ---- BN1 stats per channel d ----
__global__ void k_bn1_stats(const float* __restrict__ x, const float* __restrict__ g1,
                            const float* __restrict__ b1, float* __restrict__ ws) {
    int d = blockIdx.x, tid = threadIdx.x;
    float s = 0.f, ss = 0.f;
    for (int i = tid; i < NN * TT; i += 256) {
        int n = i / TT, t = i - n * TT;
        float v = x[((size_t)n * DD + d) * TT + t];
        s += v;
        ss = fmaf(v, v, ss);
    }
    __shared__ float rs[256], rss[256];
    rs[tid] = s; rss[tid] = ss;
    __syncthreads();
    for (int st = 128; st > 0; st >>= 1) {
        if (tid < st) { rs[tid] += rs[tid + st]; rss[tid] += rss[tid + st]; }
        __syncthreads();
    }
    if (tid == 0) {
        float m = rs[0] / (float)(NN * TT);
        float var = rss[0] / (float)(NN * TT) - m * m;
        float sc = g1[d] * rsqrtf(var + 1e-5f);
        ws[SC1 + d] = sc;
        ws[SH1 + d] = b1[d] - m * sc;
    }
}

// ---- BN1 apply + transpose to half xnT[t][n][d] ----
__global__ void k_bn1_apply(const float* __restrict__ x, float* __restrict__ ws) {
    int n = blockIdx.x, tid = threadIdx.x;
    __shared__ float lx[DD * 61];
    __shared__ float sc[DD], sh[DD];
    if (tid < DD) { sc[tid] = ws[SC1 + tid]; sh[tid] = ws[SH1 + tid]; }
    const float* xr = x + (size_t)n * DD * TT;
    for (int i = tid; i < DD * TT; i += 256) {
        int d = i / TT, t = i - d * TT;
        lx[d * 61 + t] = xr[i];
    }
    __syncthreads();
    _Float16* out = (_Float16*)ws;  // XNT
    for (int i = tid; i < TT * DD; i += 256) {
        int t = i >> 6, d = i & 63;
        out[((size_t)t * NN + n) * DD + d] = (_Float16)fmaf(lx[d * 61 + t], sc[d], sh[d]);
    }
}

// ---- LSTM: MFMA, weights persistent in VGPRs ----
// 256 blocks x 16 rows; wave w owns hidden units [w*32, w*32+32)
__global__ __launch_bounds__(256, 1) void k_lstm(float* __restrict__ ws) {
    int tid = threadIdx.x;
    int w = tid >> 6, lane = tid & 63;
    int quad = lane >> 4, m = lane & 15;
    int r0 = blockIdx.x * 16;
    __shared__ _Float16 hlds[2][16][136];  // +8 pad: 2-way-max bank aliasing (free)
    const _Float16* wf = (const _Float16*)(ws + WFRG);

    // B fragments: 48 x 16B per lane, coalesced, L2-broadcast
    h8 bw[8][6];
#pragma unroll
    for (int tg = 0; tg < 8; tg++)
#pragma unroll
        for (int ks = 0; ks < 6; ks++)
            bw[tg][ks] = *(const h8*)(wf + ((((w * 8 + tg) * 6 + ks) * 64 + lane) * 8));

    float bias[8];
#pragma unroll
    for (int tg = 0; tg < 8; tg++) {
        int g = tg >> 1, s = tg & 1;
        bias[tg] = ws[BSUM + g * 128 + w * 32 + s * 16 + m];
    }
    for (int p = tid; p < 2 * 16 * 136; p += 256) ((_Float16*)hlds)[p] = (_Float16)0.f;

    f4 cst[2] = {};
    float hv[2][4];
    const _Float16* xb = (const _Float16*)ws + (size_t)(r0 + m) * DD + quad * 8;
    __syncthreads();

    for (int t = 0; t < TT; t++) {
        // h A-frags from buffer written last step (zeros at t=0)
        h8 ah[4];
        const _Float16* hb = &hlds[(t + 1) & 1][m][quad * 8];
#pragma unroll
        for (int ks = 0; ks < 4; ks++) ah[ks] = *(const h8*)(hb + ks * 32);
        // x A-frags
        const _Float16* xp = xb + (size_t)t * NN * DD;
        h8 ax0 = *(const h8*)xp;
        h8 ax1 = *(const h8*)(xp + 32);

        f4 acc[8];
#pragma unroll
        for (int tg = 0; tg < 8; tg++) acc[tg] = (f4){bias[tg], bias[tg], bias[tg], bias[tg]};
#pragma unroll
        for (int tg = 0; tg < 8; tg++) acc[tg] = __builtin_amdgcn_mfma_f32_16x16x32_f16(ax0, bw[tg][0], acc[tg], 0, 0, 0);
#pragma unroll
        for (int tg = 0; tg < 8; tg++) acc[tg] = __builtin_amdgcn_mfma_f32_16x16x32_f16(ax1, bw[tg][1], acc[tg], 0, 0, 0);
#pragma unroll
        for (int ks = 0; ks < 4; ks++)
#pragma unroll
            for (int tg = 0; tg < 8; tg++)
                acc[tg] = __builtin_amdgcn_mfma_f32_16x16x32_f16(ah[ks], bw[tg][ks + 2], acc[tg], 0, 0, 0);

        // gate nonlinearities; c,h wave-local (C-layout: col=lane&15, row=quad*4+reg)
#pragma unroll
        for (int s = 0; s < 2; s++)
#pragma unroll
            for (int r = 0; r < 4; r++) {
                float ig = sigmoidf_(acc[s][r]);
                float fg = sigmoidf_(acc[2 + s][r]);
                float gg = tanhfast_(acc[4 + s][r]);
                float og = sigmoidf_(acc[6 + s][r]);
                float c = fmaf(fg, cst[s][r], ig * gg);
                cst[s][r] = c;
                hv[s][r] = og * tanhfast_(c);
            }
        _Float16* wbuf = &hlds[t & 1][0][0];
#pragma unroll
        for (int s = 0; s < 2; s++) {
            int col = w * 32 + s * 16 + m;
#pragma unroll
            for (int r = 0; r < 4; r++) wbuf[(quad * 4 + r) * 136 + col] = (_Float16)hv[s][r];
        }
        __syncthreads();
    }
    // final h -> HID fp32
#pragma unroll
    for (int s = 0; s < 2; s++) {
        int col = w * 32 + s * 16 + m;
#pragma unroll
        for (int r = 0; r < 4; r++)
            ws[HID + (size_t)(r0 + quad * 4 + r) * HH + col] = hv[s][r];
    }
}

// ---- BN2 stats per column k ----
__global__ void k_bn2_stats(const float* __restrict__ g2, const float* __restrict__ b2,
                            float* __restrict__ ws) {
    int k = blockIdx.x, tid = threadIdx.x;
    float s = 0.f, ss = 0.f;
    for (int n = tid; n < NN; n += 256) {
        float v = ws[HID + (size_t)n * HH + k];
        s += v;
        ss = fmaf(v, v, ss);
    }
    __shared__ float rs[256], rss[256];
    rs[tid] = s; rss[tid] = ss;
    __syncthreads();
    for (int st = 128; st > 0; st >>= 1) {
        if (tid < st) { rs[tid] += rs[tid + st]; rss[tid] += rss[tid + st]; }
        __syncthreads();
    }
    if (tid == 0) {
        float m = rs[0] / (float)NN;
        float var = rss[0] / (float)NN - m * m;
        float sc = g2[k] * rsqrtf(var + 1e-5f);
        ws[SC2 + k] = sc;
        ws[SH2 + k] = b2[k] - m * sc;
    }
}

// ---- apply BN2, compute s1, s2 ----
__global__ void k_hbn(float* __restrict__ ws) {
    __shared__ float sc[HH], sh[HH], u1s[HH], u2s[HH];
    int tid = threadIdx.x;
    if (tid < HH) {
        sc[tid] = ws[SC2 + tid]; sh[tid] = ws[SH2 + tid];
        u1s[tid] = ws[U1O + tid]; u2s[tid] = ws[U2O + tid];
    }
    __syncthreads();
    int r = tid >> 3, l = tid & 7;
    int n = blockIdx.x * 32 + r;
    const float* hr = ws + HID + (size_t)n * HH;
    float* hb = ws + HBN + (size_t)n * HH;
    float d1 = 0.f, d2 = 0.f;
    int k0 = l * 16;
#pragma unroll
    for (int q = 0; q < 16; q++) {
        int kk = k0 + q;
        float v = fmaf(hr[kk], sc[kk], sh[kk]);
        hb[kk] = v;
        d1 = fmaf(v, u1s[kk], d1);
        d2 = fmaf(v, u2s[kk], d2);
    }
#pragma unroll
    for (int o = 1; o < 8; o <<= 1) { d1 += __shfl_xor(d1, o, 64); d2 += __shfl_xor(d2, o, 64); }
    if (l == 0) {
        ws[S1O + n] = d1 + ws[CCO];
        ws[S2O + n] = d2 + ws[CCO + 1];
    }
}

// ---- softmax stats per row: max and sum of exp ----
__global__ void k_msum(float* __restrict__ ws) {
    __shared__ float ls1[NN];
    int tid = threadIdx.x;
    for (int i = tid; i < NN; i += 256) ls1[i] = ws[S1O + i];
    __syncthreads();
    int r = tid >> 3, l = tid & 7;
    int n = blockIdx.x * 32 + r;
    float s2i = ws[S2O + n];
    float m = -1e30f;
    for (int j = l; j < NN; j += 8) m = fmaxf(m, leakyf_(s2i + ls1[j]));
#pragma unroll
    for (int o = 1; o < 8; o <<= 1) m = fmaxf(m, __shfl_xor(m, o, 64));
    float se = 0.f;
    for (int j = l; j < NN; j += 8) se += __expf(leakyf_(s2i + ls1[j]) - m);
#pragma unroll
    for (int o = 1; o < 8; o <<= 1) se += __shfl_xor(se, o, 64);
    if (l == 0) { ws[MRO + n] = m; ws[SRO + n] = se; }
}

// ---- attention: h2 = softmax(scores) @ hbn + hbn ----
__global__ __launch_bounds__(256) void k_att(float* __restrict__ ws) {
    __shared__ float ls1[NN];
    int tid = threadIdx.x;
    for (int i = tid; i < NN; i += 256) ls1[i] = ws[S1O + i];
    __syncthreads();
    int rt = blockIdx.x & 15, hs = blockIdx.x >> 4;
    int n = rt * 256 + tid;
    int h0 = hs * 8;
    float s2i = ws[S2O + n];
    float mi = ws[MRO + n];
    float inv = 1.f / ws[SRO + n];
    float acc[8];
#pragma unroll
    for (int q = 0; q < 8; q++) acc[q] = 0.f;
    const float4* hb4 = (const float4*)(ws + HBN);
    int hq = h0 >> 2;
#pragma unroll 4
    for (int j = 0; j < NN; j++) {
        float wv = __expf(leakyf_(s2i + ls1[j]) - mi);
        float4 a0 = hb4[(size_t)j * 32 + hq];
        float4 a1 = hb4[(size_t)j * 32 + hq + 1];
        acc[0] = fmaf(wv, a0.x, acc[0]); acc[1] = fmaf(wv, a0.y, acc[1]);
        acc[2] = fmaf(wv, a0.z, acc[2]); acc[3] = fmaf(wv, a0.w, acc[3]);
        acc[4] = fmaf(wv, a1.x, acc[4]); acc[5] = fmaf(wv, a1.y, acc[5]);
        acc[6] = fmaf(wv, a1.z, acc[6]); acc[7] = fmaf(wv, a1.w, acc[7]);
    }
    float* h2 = ws + H2O + (size_t)n * HH + h0;
    const float* hbs = ws + HBN + (size_t)n * HH + h0;
#pragma unroll
    for (int q = 0; q < 8; q++) h2[q] = fmaf(acc[q], inv, hbs[q]);
}

// ---- final fc + leaky + out projection + sigmoid ----
__global__ __launch_bounds__(256) void k_fc(const float* __restrict__ Wfc, const float* __restrict__ bfc,
                                            const float* __restrict__ Wout, const float* __restrict__ bout,
                                            float* __restrict__ ws, float* __restrict__ out) {
    __shared__ float h2r[32][HH + 4];
    int tid = threadIdx.x;
    int n0 = blockIdx.x * 32;
    for (int p = tid; p < 32 * HH; p += 256) h2r[p >> 7][p & 127] = ws[H2O + (size_t)n0 * HH + p];
    __syncthreads();
    int r = tid >> 3, l = tid & 7;
    int n = n0 + r;
    float po = 0.f;
    for (int jj = 0; jj < 16; jj++) {
        int j = l * 16 + jj;
        const float4* wrow = (const float4*)(Wfc + (size_t)j * HH);
        float acc = 0.f;
#pragma unroll 8
        for (int q = 0; q < 32; q++) {
            float4 wv = wrow[q];
            float4 hv = *(const float4*)&h2r[r][q * 4];
            acc = fmaf(wv.x, hv.x, fmaf(wv.y, hv.y, fmaf(wv.z, hv.z, fmaf(wv.w, hv.w, acc))));
        }
        float h3 = leakyf_(acc + bfc[j]);
        po = fmaf(h3, Wout[j], po);
    }
#pragma unroll
    for (int o = 1; o < 8; o <<= 1) po += __shfl_xor(po, o, 64);
    if (l == 0) out[n] = 1.f / (1.f + __expf(-(po + bout[0])));
}

extern "C" void kernel_launch(void* const* d_in, const int* in_sizes, int n_in,
                              void* d_out, int out_size, void* d_ws, size_t ws_size,
                              hipStream_t stream) {
    const float* x = (const float*)d_in[0];
    const float* bn1_g = (const float*)d_in[1];
    const float* bn1_b = (const float*)d_in[2];
    const float* W_ih = (const float*)d_in[3];
    const float* W_hh = (const float*)d_in[4];
    const float* b_ih = (const float*)d_in[5];
    const float* b_hh = (const float*)d_in[6];
    const float* bn2_g = (const float*)d_in[7];
    const float* bn2_b = (const float*)d_in[8];
    const float* W_t = (const float*)d_in[9];
    const float* b_t = (const float*)d_in[10];
    const float* a = (const float*)d_in[11];
    const float* W_fc = (const float*)d_in[12];
    const float* b_fc = (const float*)d_in[13];
    const float* W_out = (const float*)d_in[14];
    const float* b_out = (const float*)d_in[15];
    float* ws = (float*)d_ws;
    float* out = (float*)d_out;

    k_prep_w<<<384, 256, 0, stream>>>(W_ih, W_hh, b_ih, b_hh, ws);
    k_prep_uv<<<1, 128, 0, stream>>>(W_t, b_t, a, ws);
    k_bn1_stats<<<DD, 256, 0, stream>>>(x, bn1_g, bn1_b, ws);
    k_bn1_apply<<<NN, 256, 0, stream>>>(x, ws);
    k_lstm<<<NN / 16, 256, 0, stream>>>(ws);
    k_bn2_stats<<<HH, 256, 0, stream>>>(bn2_g, bn2_b, ws);
    k_hbn<<<NN / 32, 256, 0, stream>>>(ws);
    k_msum<<<NN / 32, 256, 0, stream>>>(ws);
    k_att<<<256, 256, 0, stream>>>(ws);
    k_fc<<<NN / 32, 256, 0, stream>>>(W_fc, b_fc, W_out, b_out, ws, out);
}

// Round 3
// 433.048 us; speedup vs baseline: 6.3053x; 2.5645x over previous
//
#include <hip/hip_runtime.h>
#include <math.h>

constexpr int NN = 4096, DD = 64, TT = 60, HH = 128, GG = 512, KK = 192;

typedef _Float16 h8 __attribute__((ext_vector_type(8)));
typedef float f4 __attribute__((ext_vector_type(4)));

// ws layout (float offsets)
constexpr size_t XNT = 0;                                  // half [T][N][D]; REUSED later as swizzled hbn16
constexpr size_t WFRG = (size_t)TT * NN * DD / 2;          // half [w][tg][ks][lane][8] = 98304 halves
constexpr size_t BSUM = WFRG + 98304 / 2;                  // [512] f32
constexpr size_t SC1 = BSUM + GG;                          // [64]
constexpr size_t SH1 = SC1 + DD;                           // [64]
constexpr size_t HID = SH1 + DD;                           // [N][H] f32
constexpr size_t HBN = HID + (size_t)NN * HH;              // [N][H]
constexpr size_t SC2 = HBN + (size_t)NN * HH;              // [128]
constexpr size_t SH2 = SC2 + HH;
constexpr size_t U1O = SH2 + HH;
constexpr size_t U2O = U1O + HH;
constexpr size_t CCO = U2O + HH;                           // [4]: c1, c2, s1max
constexpr size_t S1O = CCO + 4;                            // [N]
constexpr size_t S2O = S1O + NN;
constexpr size_t H2O = S2O + NN;                           // [N][H]
constexpr size_t SSUM = H2O + (size_t)NN * HH;             // [128]: bn1 sum[64], sumsq[64]

__device__ __forceinline__ float sigmoidf_(float x) { return 1.f / (1.f + __expf(-x)); }
__device__ __forceinline__ float tanhfast_(float x) { return 1.f - 2.f / (__expf(2.f * x) + 1.f); }
__device__ __forceinline__ float leakyf_(float z) { return fmaxf(z, 0.01f * z); }

// ---- prep: per-wave-fragment swizzled fp16 weights + bias sum + zero bn1 accum ----
__global__ void k_prep_w(const float* __restrict__ Wih, const float* __restrict__ Whh,
                         const float* __restrict__ bih, const float* __restrict__ bhh,
                         float* __restrict__ ws) {
    int o = blockIdx.x * 256 + threadIdx.x;  // 0 .. 98304
    _Float16* wf = (_Float16*)(ws + WFRG);
    if (o < 98304) {
        int j = o & 7;
        int lane = (o >> 3) & 63;
        int rest = o >> 9;
        int ks = rest % 6;
        int tgw = rest / 6;          // w*8 + tg
        int tg = tgw & 7, w = tgw >> 3;
        int g = tg >> 1, s = tg & 1;
        int col = g * 128 + w * 32 + s * 16 + (lane & 15);
        int k = ks * 32 + (lane >> 4) * 8 + j;
        float v = (k < DD) ? Wih[col * DD + k] : Whh[col * HH + (k - DD)];
        wf[o] = (_Float16)v;
    }
    if (o < GG) ws[BSUM + o] = bih[o] + bhh[o];
    if (o < 128) ws[SSUM + o] = 0.f;
}

// ---- prep: u1 = W_t^T a1, u2 = W_t^T a2, c1 = b_t.a1, c2 = b_t.a2 ----
__global__ void k_prep_uv(const float* __restrict__ Wt, const float* __restrict__ bt,
                          const float* __restrict__ a, float* __restrict__ ws) {
    int k = threadIdx.x;  // 0..127
    float u1 = 0.f, u2 = 0.f;
    for (int j = 0; j < HH; j++) {
        float w = Wt[j * HH + k];
        u1 = fmaf(w, a[j], u1);
        u2 = fmaf(w, a[HH + j], u2);
    }
    ws[U1O + k] = u1;
    ws[U2O + k] = u2;
    if (k == 0) {
        float c1 = 0.f, c2 = 0.f;
        for (int j = 0; j < HH; j++) {
            c1 = fmaf(bt[j], a[j], c1);
            c2 = fmaf(bt[j], a[HH + j], c2);
        }
        ws[CCO] = c1;
        ws[CCO + 1] = c2;
    }
}

// ---- BN1 partial stats: 1024 blocks, one (n,d) row of 60 floats per thread ----
__global__ __launch_bounds__(256) void k_bn1_stats(const float* __restrict__ x, float* __restrict__ ws) {
    int tid = threadIdx.x;
    int d = tid & 63;
    int n = blockIdx.x * 4 + (tid >> 6);
    const float4* xr = (const float4*)(x + ((size_t)n * DD + d) * TT);
    float s = 0.f, ss = 0.f;
#pragma unroll
    for (int q = 0; q < 15; q++) {
        float4 v = xr[q];
        s += v.x + v.y + v.z + v.w;
        ss = fmaf(v.x, v.x, fmaf(v.y, v.y, fmaf(v.z, v.z, fmaf(v.w, v.w, ss))));
    }
    __shared__ float rs[256], rss[256];
    rs[tid] = s; rss[tid] = ss;
    __syncthreads();
    if (tid < 64) {
        float ts = rs[tid] + rs[64 + tid] + rs[128 + tid] + rs[192 + tid];
        float tss = rss[tid] + rss[64 + tid] + rss[128 + tid] + rss[192 + tid];
        atomicAdd(&ws[SSUM + tid], ts);
        atomicAdd(&ws[SSUM + 64 + tid], tss);
    }
}

// ---- BN1 finalize ----
__global__ void k_bn1_fin(const float* __restrict__ g1, const float* __restrict__ b1,
                          float* __restrict__ ws) {
    int d = threadIdx.x;  // 0..63
    float cnt = (float)(NN * TT);
    float m = ws[SSUM + d] / cnt;
    float var = ws[SSUM + 64 + d] / cnt - m * m;
    float sc = g1[d] * rsqrtf(var + 1e-5f);
    ws[SC1 + d] = sc;
    ws[SH1 + d] = b1[d] - m * sc;
}

// ---- BN1 apply + transpose to half xnT[t][n][d] ----
__global__ void k_bn1_apply(const float* __restrict__ x, float* __restrict__ ws) {
    int n = blockIdx.x, tid = threadIdx.x;
    __shared__ float lx[DD * 61];
    __shared__ float sc[DD], sh[DD];
    if (tid < DD) { sc[tid] = ws[SC1 + tid]; sh[tid] = ws[SH1 + tid]; }
    const float* xr = x + (size_t)n * DD * TT;
    for (int i = tid; i < DD * TT; i += 256) {
        int d = i / TT, t = i - d * TT;
        lx[d * 61 + t] = xr[i];
    }
    __syncthreads();
    _Float16* out = (_Float16*)ws;  // XNT
    for (int i = tid; i < TT * DD; i += 256) {
        int t = i >> 6, d = i & 63;
        out[((size_t)t * NN + n) * DD + d] = (_Float16)fmaf(lx[d * 61 + t], sc[d], sh[d]);
    }
}

// ---- LSTM: MFMA, weights persistent in VGPRs ----
__global__ __launch_bounds__(256, 1) void k_lstm(float* __restrict__ ws) {
    int tid = threadIdx.x;
    int w = tid >> 6, lane = tid & 63;
    int quad = lane >> 4, m = lane & 15;
    int r0 = blockIdx.x * 16;
    __shared__ _Float16 hlds[2][16][136];
    const _Float16* wf = (const _Float16*)(ws + WFRG);

    h8 bw[8][6];
#pragma unroll
    for (int tg = 0; tg < 8; tg++)
#pragma unroll
        for (int ks = 0; ks < 6; ks++)
            bw[tg][ks] = *(const h8*)(wf + ((((w * 8 + tg) * 6 + ks) * 64 + lane) * 8));

    float bias[8];
#pragma unroll
    for (int tg = 0; tg < 8; tg++) {
        int g = tg >> 1, s = tg & 1;
        bias[tg] = ws[BSUM + g * 128 + w * 32 + s * 16 + m];
    }
    for (int p = tid; p < 2 * 16 * 136; p += 256) ((_Float16*)hlds)[p] = (_Float16)0.f;

    f4 cst[2] = {};
    float hv[2][4];
    const _Float16* xb = (const _Float16*)ws + (size_t)(r0 + m) * DD + quad * 8;
    __syncthreads();

    for (int t = 0; t < TT; t++) {
        h8 ah[4];
        const _Float16* hb = &hlds[(t + 1) & 1][m][quad * 8];
#pragma unroll
        for (int ks = 0; ks < 4; ks++) ah[ks] = *(const h8*)(hb + ks * 32);
        const _Float16* xp = xb + (size_t)t * NN * DD;
        h8 ax0 = *(const h8*)xp;
        h8 ax1 = *(const h8*)(xp + 32);

        f4 acc[8];
#pragma unroll
        for (int tg = 0; tg < 8; tg++) acc[tg] = (f4){bias[tg], bias[tg], bias[tg], bias[tg]};
#pragma unroll
        for (int tg = 0; tg < 8; tg++) acc[tg] = __builtin_amdgcn_mfma_f32_16x16x32_f16(ax0, bw[tg][0], acc[tg], 0, 0, 0);
#pragma unroll
        for (int tg = 0; tg < 8; tg++) acc[tg] = __builtin_amdgcn_mfma_f32_16x16x32_f16(ax1, bw[tg][1], acc[tg], 0, 0, 0);
#pragma unroll
        for (int ks = 0; ks < 4; ks++)
#pragma unroll
            for (int tg = 0; tg < 8; tg++)
                acc[tg] = __builtin_amdgcn_mfma_f32_16x16x32_f16(ah[ks], bw[tg][ks + 2], acc[tg], 0, 0, 0);

#pragma unroll
        for (int s = 0; s < 2; s++)
#pragma unroll
            for (int r = 0; r < 4; r++) {
                float ig = sigmoidf_(acc[s][r]);
                float fg = sigmoidf_(acc[2 + s][r]);
                float gg = tanhfast_(acc[4 + s][r]);
                float og = sigmoidf_(acc[6 + s][r]);
                float c = fmaf(fg, cst[s][r], ig * gg);
                cst[s][r] = c;
                hv[s][r] = og * tanhfast_(c);
            }
        _Float16* wbuf = &hlds[t & 1][0][0];
#pragma unroll
        for (int s = 0; s < 2; s++) {
            int col = w * 32 + s * 16 + m;
#pragma unroll
            for (int r = 0; r < 4; r++) wbuf[(quad * 4 + r) * 136 + col] = (_Float16)hv[s][r];
        }
        __syncthreads();
    }
#pragma unroll
    for (int s = 0; s < 2; s++) {
        int col = w * 32 + s * 16 + m;
#pragma unroll
        for (int r = 0; r < 4; r++)
            ws[HID + (size_t)(r0 + quad * 4 + r) * HH + col] = hv[s][r];
    }
}

// ---- BN2 stats per column k ----
__global__ void k_bn2_stats(const float* __restrict__ g2, const float* __restrict__ b2,
                            float* __restrict__ ws) {
    int k = blockIdx.x, tid = threadIdx.x;
    float s = 0.f, ss = 0.f;
    for (int n = tid; n < NN; n += 256) {
        float v = ws[HID + (size_t)n * HH + k];
        s += v;
        ss = fmaf(v, v, ss);
    }
    __shared__ float rs[256], rss[256];
    rs[tid] = s; rss[tid] = ss;
    __syncthreads();
    for (int st = 128; st > 0; st >>= 1) {
        if (tid < st) { rs[tid] += rs[tid + st]; rss[tid] += rss[tid + st]; }
        __syncthreads();
    }
    if (tid == 0) {
        float m = rs[0] / (float)NN;
        float var = rss[0] / (float)NN - m * m;
        float sc = g2[k] * rsqrtf(var + 1e-5f);
        ws[SC2 + k] = sc;
        ws[SH2 + k] = b2[k] - m * sc;
    }
}

// ---- apply BN2, compute s1, s2, write fp32 hbn + swizzled fp16 hbn (at ws+0) ----
__global__ void k_hbn(float* __restrict__ ws) {
    __shared__ float sc[HH], sh[HH], u1s[HH], u2s[HH];
    int tid = threadIdx.x;
    if (tid < HH) {
        sc[tid] = ws[SC2 + tid]; sh[tid] = ws[SH2 + tid];
        u1s[tid] = ws[U1O + tid]; u2s[tid] = ws[U2O + tid];
    }
    __syncthreads();
    int r = tid >> 3, l = tid & 7;
    int n = blockIdx.x * 32 + r;
    const float* hr = ws + HID + (size_t)n * HH;
    float* hb = ws + HBN + (size_t)n * HH;
    _Float16* hsw = (_Float16*)ws;  // swizzled hbn16 (XNT region, dead after lstm)
    int jt = n >> 5;
    int lanehi = (n >> 3) & 3;
    int jj = n & 7;
    float d1 = 0.f, d2 = 0.f;
    int k0 = l * 16;
#pragma unroll
    for (int q = 0; q < 16; q++) {
        int kk = k0 + q;
        float v = fmaf(hr[kk], sc[kk], sh[kk]);
        hb[kk] = v;
        int hgroup = kk >> 4;
        int lane_s = lanehi * 16 + (kk & 15);
        hsw[((size_t)(jt * 8 + hgroup) * 64 + lane_s) * 8 + jj] = (_Float16)v;
        d1 = fmaf(v, u1s[kk], d1);
        d2 = fmaf(v, u2s[kk], d2);
    }
#pragma unroll
    for (int o = 1; o < 8; o <<= 1) { d1 += __shfl_xor(d1, o, 64); d2 += __shfl_xor(d2, o, 64); }
    if (l == 0) {
        ws[S1O + n] = d1 + ws[CCO];
        ws[S2O + n] = d2 + ws[CCO + 1];
    }
}

// ---- s1max (leaky is monotone: row max = leaky(s2_i + max_j s1_j)) ----
__global__ void k_smax(float* __restrict__ ws) {
    __shared__ float red[4];
    int tid = threadIdx.x;
    float m = -1e30f;
    for (int i = tid; i < NN; i += 256) m = fmaxf(m, ws[S1O + i]);
#pragma unroll
    for (int o = 32; o > 0; o >>= 1) m = fmaxf(m, __shfl_xor(m, o, 64));
    if ((tid & 63) == 0) red[tid >> 6] = m;
    __syncthreads();
    if (tid == 0) ws[CCO + 2] = fmaxf(fmaxf(red[0], red[1]), fmaxf(red[2], red[3]));
}

// ---- attention: MFMA flash-style, fused row-sum, h2 = softmax @ hbn + hbn ----
__global__ __launch_bounds__(256, 1) void k_att(float* __restrict__ ws) {
    __shared__ float ls1[NN];
    __shared__ float rowsum[16];
    int tid = threadIdx.x;
    int w = tid >> 6, lane = tid & 63;
    int quad = lane >> 4, m = lane & 15;
    int n0 = blockIdx.x * 16;
    for (int i = tid; i < NN; i += 256) ls1[i] = ws[S1O + i];
    __syncthreads();
    float s1max = ws[CCO + 2];
    float s2n = ws[S2O + n0 + m];
    float mi = leakyf_(s2n + s1max);
    const _Float16* hbsw = (const _Float16*)ws;
    f4 acc0 = {}, acc1 = {};
    float psum = 0.f;
    int hg0 = w * 2, hg1 = w * 2 + 1;
    for (int jt = 0; jt < 128; jt++) {
        const float* sp = &ls1[jt * 32 + quad * 8];
        h8 ap;
        float ps = 0.f;
#pragma unroll
        for (int jj = 0; jj < 8; jj++) {
            float z = s2n + sp[jj];
            float p = __expf(leakyf_(z) - mi);
            ps += p;
            ap[jj] = (_Float16)p;
        }
        psum += ps;
        h8 b0 = *(const h8*)(hbsw + ((size_t)(jt * 8 + hg0) * 64 + lane) * 8);
        h8 b1 = *(const h8*)(hbsw + ((size_t)(jt * 8 + hg1) * 64 + lane) * 8);
        acc0 = __builtin_amdgcn_mfma_f32_16x16x32_f16(ap, b0, acc0, 0, 0, 0);
        acc1 = __builtin_amdgcn_mfma_f32_16x16x32_f16(ap, b1, acc1, 0, 0, 0);
    }
    psum += __shfl_xor(psum, 16, 64);
    psum += __shfl_xor(psum, 32, 64);
    if (w == 0 && lane < 16) rowsum[lane] = psum;
    __syncthreads();
    float invs[4];
#pragma unroll
    for (int r = 0; r < 4; r++) invs[r] = 1.f / rowsum[quad * 4 + r];
#pragma unroll
    for (int s = 0; s < 2; s++) {
        int h = w * 32 + s * 16 + m;
        f4 a = s ? acc1 : acc0;
#pragma unroll
        for (int r = 0; r < 4; r++) {
            int n = n0 + quad * 4 + r;
            ws[H2O + (size_t)n * HH + h] = fmaf(a[r], invs[r], ws[HBN + (size_t)n * HH + h]);
        }
    }
}

// ---- final fc + leaky + out projection + sigmoid ----
__global__ __launch_bounds__(256) void k_fc(const float* __restrict__ Wfc, const float* __restrict__ bfc,
                                            const float* __restrict__ Wout, const float* __restrict__ bout,
                                            float* __restrict__ ws, float* __restrict__ out) {
    __shared__ float h2r[32][HH + 4];
    int tid = threadIdx.x;
    int n0 = blockIdx.x * 32;
    for (int p = tid; p < 32 * HH; p += 256) h2r[p >> 7][p & 127] = ws[H2O + (size_t)n0 * HH + p];
    __syncthreads();
    int r = tid >> 3, l = tid & 7;
    int n = n0 + r;
    float po = 0.f;
    for (int jj = 0; jj < 16; jj++) {
        int j = l * 16 + jj;
        const float4* wrow = (const float4*)(Wfc + (size_t)j * HH);
        float acc = 0.f;
#pragma unroll 8
        for (int q = 0; q < 32; q++) {
            float4 wv = wrow[q];
            float4 hv = *(const float4*)&h2r[r][q * 4];
            acc = fmaf(wv.x, hv.x, fmaf(wv.y, hv.y, fmaf(wv.z, hv.z, fmaf(wv.w, hv.w, acc))));
        }
        float h3 = leakyf_(acc + bfc[j]);
        po = fmaf(h3, Wout[j], po);
    }
#pragma unroll
    for (int o = 1; o < 8; o <<= 1) po += __shfl_xor(po, o, 64);
    if (l == 0) out[n] = 1.f / (1.f + __expf(-(po + bout[0])));
}

extern "C" void kernel_launch(void* const* d_in, const int* in_sizes, int n_in,
                              void* d_out, int out_size, void* d_ws, size_t ws_size,
                              hipStream_t stream) {
    const float* x = (const float*)d_in[0];
    const float* bn1_g = (const float*)d_in[1];
    const float* bn1_b = (const float*)d_in[2];
    const float* W_ih = (const float*)d_in[3];
    const float* W_hh = (const float*)d_in[4];
    const float* b_ih = (const float*)d_in[5];
    const float* b_hh = (const float*)d_in[6];
    const float* bn2_g = (const float*)d_in[7];
    const float* bn2_b = (const float*)d_in[8];
    const float* W_t = (const float*)d_in[9];
    const float* b_t = (const float*)d_in[10];
    const float* a = (const float*)d_in[11];
    const float* W_fc = (const float*)d_in[12];
    const float* b_fc = (const float*)d_in[13];
    const float* W_out = (const float*)d_in[14];
    const float* b_out = (const float*)d_in[15];
    float* ws = (float*)d_ws;
    float* out = (float*)d_out;

    k_prep_w<<<384, 256, 0, stream>>>(W_ih, W_hh, b_ih, b_hh, ws);
    k_prep_uv<<<1, 128, 0, stream>>>(W_t, b_t, a, ws);
    k_bn1_stats<<<NN / 4, 256, 0, stream>>>(x, ws);
    k_bn1_fin<<<1, 64, 0, stream>>>(bn1_g, bn1_b, ws);
    k_bn1_apply<<<NN, 256, 0, stream>>>(x, ws);
    k_lstm<<<NN / 16, 256, 0, stream>>>(ws);
    k_bn2_stats<<<HH, 256, 0, stream>>>(bn2_g, bn2_b, ws);
    k_hbn<<<NN / 32, 256, 0, stream>>>(ws);
    k_smax<<<1, 256, 0, stream>>>(ws);
    k_att<<<NN / 16, 256, 0, stream>>>(ws);
    k_fc<<<NN / 32, 256, 0, stream>>>(W_fc, b_fc, W_out, b_out, ws, out);
}

// Round 4
// 400.816 us; speedup vs baseline: 6.8124x; 1.0804x over previous
//
#include <hip/hip_runtime.h>
#include <math.h>

constexpr int NN = 4096, DD = 64, TT = 60, HH = 128, GG = 512, KK = 192;

typedef _Float16 h8 __attribute__((ext_vector_type(8)));
typedef float f4 __attribute__((ext_vector_type(4)));

// ws layout (float offsets)
constexpr size_t XNT = 0;                                  // half [T][N][D]; REUSED later as swizzled hbn16
constexpr size_t WFRG = (size_t)TT * NN * DD / 2;          // half [w][g][ks][lane][8] = 98304 halves
constexpr size_t BSUM = WFRG + 98304 / 2;                  // [512] f32
constexpr size_t SC1 = BSUM + GG;                          // [64]
constexpr size_t SH1 = SC1 + DD;                           // [64]
constexpr size_t HID = SH1 + DD;                           // [N][H] f32
constexpr size_t HBN = HID + (size_t)NN * HH;              // [N][H]
constexpr size_t SC2 = HBN + (size_t)NN * HH;              // [128]
constexpr size_t SH2 = SC2 + HH;
constexpr size_t U1O = SH2 + HH;
constexpr size_t U2O = U1O + HH;
constexpr size_t CCO = U2O + HH;                           // [4]: c1, c2, s1max(encoded uint)
constexpr size_t S1O = CCO + 4;                            // [N]
constexpr size_t S2O = S1O + NN;
constexpr size_t H2O = S2O + NN;                           // [N][H]
constexpr size_t SSUM = H2O + (size_t)NN * HH;             // [128]: bn1 sum[64], sumsq[64]

__device__ __forceinline__ float sigmoidf_(float x) { return 1.f / (1.f + __expf(-x)); }
__device__ __forceinline__ float tanhfast_(float x) { return 1.f - 2.f / (__expf(2.f * x) + 1.f); }
__device__ __forceinline__ float leakyf_(float z) { return fmaxf(z, 0.01f * z); }

// monotone float<->uint encoding for atomicMax over signed floats
__device__ __forceinline__ unsigned fenc_(float f) {
    unsigned b = __float_as_uint(f);
    return (b & 0x80000000u) ? ~b : (b | 0x80000000u);
}
__device__ __forceinline__ float fdec_(unsigned u) {
    return (u & 0x80000000u) ? __uint_as_float(u & 0x7fffffffu) : __uint_as_float(~u);
}

// ---- prep: per-wave-fragment swizzled fp16 weights + bias sum + zero bn1 accum ----
// frag (w,g,ks): value = W[k][col], col = g*128 + w*16 + (lane&15), k = ks*32 + (lane>>4)*8 + j
__global__ void k_prep_w(const float* __restrict__ Wih, const float* __restrict__ Whh,
                         const float* __restrict__ bih, const float* __restrict__ bhh,
                         float* __restrict__ ws) {
    int o = blockIdx.x * 256 + threadIdx.x;  // 0 .. 98304
    _Float16* wf = (_Float16*)(ws + WFRG);
    if (o < 98304) {
        int j = o & 7;
        int lane = (o >> 3) & 63;
        int rest = o >> 9;           // 0..191
        int ks = rest % 6;
        int gw = rest / 6;           // w*4 + g
        int g = gw & 3, w = gw >> 2;
        int col = g * 128 + w * 16 + (lane & 15);
        int k = ks * 32 + (lane >> 4) * 8 + j;
        float v = (k < DD) ? Wih[col * DD + k] : Whh[col * HH + (k - DD)];
        wf[o] = (_Float16)v;
    }
    if (o < GG) ws[BSUM + o] = bih[o] + bhh[o];
    if (o < 128) ws[SSUM + o] = 0.f;
}

// ---- prep: u1 = W_t^T a1, u2 = W_t^T a2, c1 = b_t.a1, c2 = b_t.a2; init s1max accum ----
__global__ void k_prep_uv(const float* __restrict__ Wt, const float* __restrict__ bt,
                          const float* __restrict__ a, float* __restrict__ ws) {
    int k = threadIdx.x;  // 0..127
    float u1 = 0.f, u2 = 0.f;
    for (int j = 0; j < HH; j++) {
        float w = Wt[j * HH + k];
        u1 = fmaf(w, a[j], u1);
        u2 = fmaf(w, a[HH + j], u2);
    }
    ws[U1O + k] = u1;
    ws[U2O + k] = u2;
    if (k == 0) {
        float c1 = 0.f, c2 = 0.f;
        for (int j = 0; j < HH; j++) {
            c1 = fmaf(bt[j], a[j], c1);
            c2 = fmaf(bt[j], a[HH + j], c2);
        }
        ws[CCO] = c1;
        ws[CCO + 1] = c2;
        ((unsigned*)ws)[CCO + 2] = fenc_(-1e30f);
    }
}

// ---- BN1 partial stats: 1024 blocks, one (n,d) row of 60 floats per thread ----
__global__ __launch_bounds__(256) void k_bn1_stats(const float* __restrict__ x, float* __restrict__ ws) {
    int tid = threadIdx.x;
    int d = tid & 63;
    int n = blockIdx.x * 4 + (tid >> 6);
    const float4* xr = (const float4*)(x + ((size_t)n * DD + d) * TT);
    float s = 0.f, ss = 0.f;
#pragma unroll
    for (int q = 0; q < 15; q++) {
        float4 v = xr[q];
        s += v.x + v.y + v.z + v.w;
        ss = fmaf(v.x, v.x, fmaf(v.y, v.y, fmaf(v.z, v.z, fmaf(v.w, v.w, ss))));
    }
    __shared__ float rs[256], rss[256];
    rs[tid] = s; rss[tid] = ss;
    __syncthreads();
    if (tid < 64) {
        float ts = rs[tid] + rs[64 + tid] + rs[128 + tid] + rs[192 + tid];
        float tss = rss[tid] + rss[64 + tid] + rss[128 + tid] + rss[192 + tid];
        atomicAdd(&ws[SSUM + tid], ts);
        atomicAdd(&ws[SSUM + 64 + tid], tss);
    }
}

// ---- BN1 finalize ----
__global__ void k_bn1_fin(const float* __restrict__ g1, const float* __restrict__ b1,
                          float* __restrict__ ws) {
    int d = threadIdx.x;  // 0..63
    float cnt = (float)(NN * TT);
    float m = ws[SSUM + d] / cnt;
    float var = ws[SSUM + 64 + d] / cnt - m * m;
    float sc = g1[d] * rsqrtf(var + 1e-5f);
    ws[SC1 + d] = sc;
    ws[SH1 + d] = b1[d] - m * sc;
}

// ---- BN1 apply + transpose to half xnT[t][n][d] ----
__global__ void k_bn1_apply(const float* __restrict__ x, float* __restrict__ ws) {
    int n = blockIdx.x, tid = threadIdx.x;
    __shared__ float lx[DD * 61];
    __shared__ float sc[DD], sh[DD];
    if (tid < DD) { sc[tid] = ws[SC1 + tid]; sh[tid] = ws[SH1 + tid]; }
    const float* xr = x + (size_t)n * DD * TT;
    for (int i = tid; i < DD * TT; i += 256) {
        int d = i / TT, t = i - d * TT;
        lx[d * 61 + t] = xr[i];
    }
    __syncthreads();
    _Float16* out = (_Float16*)ws;  // XNT
    for (int i = tid; i < TT * DD; i += 256) {
        int t = i >> 6, d = i & 63;
        out[((size_t)t * NN + n) * DD + d] = (_Float16)fmaf(lx[d * 61 + t], sc[d], sh[d]);
    }
}

// ---- LSTM: MFMA, weights persistent in VGPRs; 8 waves/block -> 2 waves/SIMD ----
// wave w owns hidden cols [w*16, w*16+16); 256 blocks x 16 rows
__global__ __launch_bounds__(512, 1) void k_lstm(float* __restrict__ ws) {
    int tid = threadIdx.x;
    int w = tid >> 6, lane = tid & 63;
    int quad = lane >> 4, m = lane & 15;
    int r0 = blockIdx.x * 16;
    __shared__ _Float16 hlds[2][16][136];
    const _Float16* wf = (const _Float16*)(ws + WFRG);

    h8 bw[4][6];
#pragma unroll
    for (int g = 0; g < 4; g++)
#pragma unroll
        for (int ks = 0; ks < 6; ks++)
            bw[g][ks] = *(const h8*)(wf + ((((w * 4 + g) * 6 + ks) * 64 + lane) * 8));

    float bias[4];
#pragma unroll
    for (int g = 0; g < 4; g++) bias[g] = ws[BSUM + g * 128 + w * 16 + m];

    for (int p = tid; p < 2 * 16 * 136; p += 512) ((_Float16*)hlds)[p] = (_Float16)0.f;

    f4 cst = {};
    float hv[4];
    const _Float16* xb = (const _Float16*)ws + (size_t)(r0 + m) * DD + quad * 8;
    __syncthreads();

    h8 ax0 = *(const h8*)xb;
    h8 ax1 = *(const h8*)(xb + 32);

    for (int t = 0; t < TT; t++) {
        // h A-frags from buffer written last step (zeros at t=0)
        h8 ah[4];
        const _Float16* hb = &hlds[(t + 1) & 1][m][quad * 8];
#pragma unroll
        for (int ks = 0; ks < 4; ks++) ah[ks] = *(const h8*)(hb + ks * 32);
        // prefetch next-step x
        h8 nx0 = {}, nx1 = {};
        if (t + 1 < TT) {
            const _Float16* xp = xb + (size_t)(t + 1) * NN * DD;
            nx0 = *(const h8*)xp;
            nx1 = *(const h8*)(xp + 32);
        }

        f4 acc[4];
#pragma unroll
        for (int g = 0; g < 4; g++) acc[g] = (f4){bias[g], bias[g], bias[g], bias[g]};
#pragma unroll
        for (int g = 0; g < 4; g++) acc[g] = __builtin_amdgcn_mfma_f32_16x16x32_f16(ax0, bw[g][0], acc[g], 0, 0, 0);
#pragma unroll
        for (int g = 0; g < 4; g++) acc[g] = __builtin_amdgcn_mfma_f32_16x16x32_f16(ax1, bw[g][1], acc[g], 0, 0, 0);
#pragma unroll
        for (int ks = 0; ks < 4; ks++)
#pragma unroll
            for (int g = 0; g < 4; g++)
                acc[g] = __builtin_amdgcn_mfma_f32_16x16x32_f16(ah[ks], bw[g][ks + 2], acc[g], 0, 0, 0);

        // gates; c,h wave-local (C-layout: col=lane&15, row=quad*4+reg)
#pragma unroll
        for (int r = 0; r < 4; r++) {
            float ig = sigmoidf_(acc[0][r]);
            float fg = sigmoidf_(acc[1][r]);
            float gg = tanhfast_(acc[2][r]);
            float og = sigmoidf_(acc[3][r]);
            float c = fmaf(fg, cst[r], ig * gg);
            cst[r] = c;
            hv[r] = og * tanhfast_(c);
        }
        _Float16* wbuf = &hlds[t & 1][0][0];
        int col = w * 16 + m;
#pragma unroll
        for (int r = 0; r < 4; r++) wbuf[(quad * 4 + r) * 136 + col] = (_Float16)hv[r];
        __syncthreads();
        ax0 = nx0; ax1 = nx1;
    }
    // final h -> HID fp32
    int col = w * 16 + m;
#pragma unroll
    for (int r = 0; r < 4; r++)
        ws[HID + (size_t)(r0 + quad * 4 + r) * HH + col] = hv[r];
}

// ---- BN2 stats per column k ----
__global__ void k_bn2_stats(const float* __restrict__ g2, const float* __restrict__ b2,
                            float* __restrict__ ws) {
    int k = blockIdx.x, tid = threadIdx.x;
    float s = 0.f, ss = 0.f;
    for (int n = tid; n < NN; n += 256) {
        float v = ws[HID + (size_t)n * HH + k];
        s += v;
        ss = fmaf(v, v, ss);
    }
    __shared__ float rs[256], rss[256];
    rs[tid] = s; rss[tid] = ss;
    __syncthreads();
    for (int st = 128; st > 0; st >>= 1) {
        if (tid < st) { rs[tid] += rs[tid + st]; rss[tid] += rss[tid + st]; }
        __syncthreads();
    }
    if (tid == 0) {
        float m = rs[0] / (float)NN;
        float var = rss[0] / (float)NN - m * m;
        float sc = g2[k] * rsqrtf(var + 1e-5f);
        ws[SC2 + k] = sc;
        ws[SH2 + k] = b2[k] - m * sc;
    }
}

// ---- apply BN2, compute s1, s2, fp32 hbn + swizzled fp16 hbn + s1max atomic ----
__global__ void k_hbn(float* __restrict__ ws) {
    __shared__ float sc[HH], sh[HH], u1s[HH], u2s[HH];
    int tid = threadIdx.x;
    if (tid < HH) {
        sc[tid] = ws[SC2 + tid]; sh[tid] = ws[SH2 + tid];
        u1s[tid] = ws[U1O + tid]; u2s[tid] = ws[U2O + tid];
    }
    __syncthreads();
    int r = tid >> 3, l = tid & 7;
    int n = blockIdx.x * 32 + r;
    const float* hr = ws + HID + (size_t)n * HH;
    float* hb = ws + HBN + (size_t)n * HH;
    _Float16* hsw = (_Float16*)ws;  // swizzled hbn16 (XNT region, dead after lstm)
    int jt = n >> 5;
    int lanehi = (n >> 3) & 3;
    int jj = n & 7;
    float d1 = 0.f, d2 = 0.f;
    int k0 = l * 16;
#pragma unroll
    for (int q = 0; q < 16; q++) {
        int kk = k0 + q;
        float v = fmaf(hr[kk], sc[kk], sh[kk]);
        hb[kk] = v;
        int hgroup = kk >> 4;
        int lane_s = lanehi * 16 + (kk & 15);
        hsw[((size_t)(jt * 8 + hgroup) * 64 + lane_s) * 8 + jj] = (_Float16)v;
        d1 = fmaf(v, u1s[kk], d1);
        d2 = fmaf(v, u2s[kk], d2);
    }
#pragma unroll
    for (int o = 1; o < 8; o <<= 1) { d1 += __shfl_xor(d1, o, 64); d2 += __shfl_xor(d2, o, 64); }
    if (l == 0) {
        float s1 = d1 + ws[CCO];
        ws[S1O + n] = s1;
        ws[S2O + n] = d2 + ws[CCO + 1];
        atomicMax((unsigned*)ws + CCO + 2, fenc_(s1));
    }
}

// ---- attention: MFMA flash-style, fused row-sum, h2 = softmax @ hbn + hbn ----
// leaky is monotone: row max = leaky(s2_i + max_j s1_j)
__global__ __launch_bounds__(256, 1) void k_att(float* __restrict__ ws) {
    __shared__ float ls1[NN];
    __shared__ float rowsum[16];
    int tid = threadIdx.x;
    int w = tid >> 6, lane = tid & 63;
    int quad = lane >> 4, m = lane & 15;
    int n0 = blockIdx.x * 16;
    for (int i = tid; i < NN; i += 256) ls1[i] = ws[S1O + i];
    __syncthreads();
    float s1max = fdec_(((unsigned*)ws)[CCO + 2]);
    float s2n = ws[S2O + n0 + m];
    float mi = leakyf_(s2n + s1max);
    const _Float16* hbsw = (const _Float16*)ws;
    f4 acc0 = {}, acc1 = {};
    float psum = 0.f;
    int hg0 = w * 2, hg1 = w * 2 + 1;
    for (int jt = 0; jt < 128; jt++) {
        const float* sp = &ls1[jt * 32 + quad * 8];
        h8 ap;
        float ps = 0.f;
#pragma unroll
        for (int jj = 0; jj < 8; jj++) {
            float z = s2n + sp[jj];
            float p = __expf(leakyf_(z) - mi);
            ps += p;
            ap[jj] = (_Float16)p;
        }
        psum += ps;
        h8 b0 = *(const h8*)(hbsw + ((size_t)(jt * 8 + hg0) * 64 + lane) * 8);
        h8 b1 = *(const h8*)(hbsw + ((size_t)(jt * 8 + hg1) * 64 + lane) * 8);
        acc0 = __builtin_amdgcn_mfma_f32_16x16x32_f16(ap, b0, acc0, 0, 0, 0);
        acc1 = __builtin_amdgcn_mfma_f32_16x16x32_f16(ap, b1, acc1, 0, 0, 0);
    }
    psum += __shfl_xor(psum, 16, 64);
    psum += __shfl_xor(psum, 32, 64);
    if (w == 0 && lane < 16) rowsum[lane] = psum;
    __syncthreads();
    float invs[4];
#pragma unroll
    for (int r = 0; r < 4; r++) invs[r] = 1.f / rowsum[quad * 4 + r];
#pragma unroll
    for (int s = 0; s < 2; s++) {
        int h = w * 32 + s * 16 + m;
        f4 a = s ? acc1 : acc0;
#pragma unroll
        for (int r = 0; r < 4; r++) {
            int n = n0 + quad * 4 + r;
            ws[H2O + (size_t)n * HH + h] = fmaf(a[r], invs[r], ws[HBN + (size_t)n * HH + h]);
        }
    }
}

// ---- final fc + leaky + out projection + sigmoid ----
__global__ __launch_bounds__(256) void k_fc(const float* __restrict__ Wfc, const float* __restrict__ bfc,
                                            const float* __restrict__ Wout, const float* __restrict__ bout,
                                            float* __restrict__ ws, float* __restrict__ out) {
    __shared__ float h2r[32][HH + 4];
    int tid = threadIdx.x;
    int n0 = blockIdx.x * 32;
    for (int p = tid; p < 32 * HH; p += 256) h2r[p >> 7][p & 127] = ws[H2O + (size_t)n0 * HH + p];
    __syncthreads();
    int r = tid >> 3, l = tid & 7;
    int n = n0 + r;
    float po = 0.f;
    for (int jj = 0; jj < 16; jj++) {
        int j = l * 16 + jj;
        const float4* wrow = (const float4*)(Wfc + (size_t)j * HH);
        float acc = 0.f;
#pragma unroll 8
        for (int q = 0; q < 32; q++) {
            float4 wv = wrow[q];
            float4 hv = *(const float4*)&h2r[r][q * 4];
            acc = fmaf(wv.x, hv.x, fmaf(wv.y, hv.y, fmaf(wv.z, hv.z, fmaf(wv.w, hv.w, acc))));
        }
        float h3 = leakyf_(acc + bfc[j]);
        po = fmaf(h3, Wout[j], po);
    }
#pragma unroll
    for (int o = 1; o < 8; o <<= 1) po += __shfl_xor(po, o, 64);
    if (l == 0) out[n] = 1.f / (1.f + __expf(-(po + bout[0])));
}

extern "C" void kernel_launch(void* const* d_in, const int* in_sizes, int n_in,
                              void* d_out, int out_size, void* d_ws, size_t ws_size,
                              hipStream_t stream) {
    const float* x = (const float*)d_in[0];
    const float* bn1_g = (const float*)d_in[1];
    const float* bn1_b = (const float*)d_in[2];
    const float* W_ih = (const float*)d_in[3];
    const float* W_hh = (const float*)d_in[4];
    const float* b_ih = (const float*)d_in[5];
    const float* b_hh = (const float*)d_in[6];
    const float* bn2_g = (const float*)d_in[7];
    const float* bn2_b = (const float*)d_in[8];
    const float* W_t = (const float*)d_in[9];
    const float* b_t = (const float*)d_in[10];
    const float* a = (const float*)d_in[11];
    const float* W_fc = (const float*)d_in[12];
    const float* b_fc = (const float*)d_in[13];
    const float* W_out = (const float*)d_in[14];
    const float* b_out = (const float*)d_in[15];
    float* ws = (float*)d_ws;
    float* out = (float*)d_out;

    k_prep_w<<<384, 256, 0, stream>>>(W_ih, W_hh, b_ih, b_hh, ws);
    k_prep_uv<<<1, 128, 0, stream>>>(W_t, b_t, a, ws);
    k_bn1_stats<<<NN / 4, 256, 0, stream>>>(x, ws);
    k_bn1_fin<<<1, 64, 0, stream>>>(bn1_g, bn1_b, ws);
    k_bn1_apply<<<NN, 256, 0, stream>>>(x, ws);
    k_lstm<<<NN / 16, 512, 0, stream>>>(ws);
    k_bn2_stats<<<HH, 256, 0, stream>>>(bn2_g, bn2_b, ws);
    k_hbn<<<NN / 32, 256, 0, stream>>>(ws);
    k_att<<<NN / 16, 256, 0, stream>>>(ws);
    k_fc<<<NN / 32, 256, 0, stream>>>(W_fc, b_fc, W_out, b_out, ws, out);
}